// Round 10
// baseline (225.601 us; speedup 1.0000x reference)
//
#include <hip/hip_runtime.h>
#include <stdint.h>
#include <math.h>

#define BB 2
#define SS 2048
#define DDIM 512
#define HH 8
#define HDD 64

typedef unsigned short u16;
typedef unsigned int u32;
typedef unsigned long long u64;
typedef short bf16x8 __attribute__((ext_vector_type(8)));
typedef float f32x4 __attribute__((ext_vector_type(4)));

__device__ __forceinline__ u16 f2bf(float x) {
  unsigned int u = __float_as_uint(x);
  unsigned int r = (u + 0x7fffu + ((u >> 16) & 1u)) >> 16; // RNE
  return (u16)r;
}

__device__ __forceinline__ u32 cvtpk(float a, float b) {
  u32 r;
  asm("v_cvt_pk_bf16_f32 %0, %1, %2" : "=v"(r) : "v"(a), "v"(b));
  return r;
}

// async global->LDS, 16B per lane. LDS dest must be wave-uniform base + lane*16.
__device__ __forceinline__ void cp16(const void* g, void* l) {
  __builtin_amdgcn_global_load_lds(
      (const __attribute__((address_space(1))) void*)g,
      (__attribute__((address_space(3))) void*)l, 16, 0, 0);
}

// ---------------- cast gene/expr fp32 -> bf16 ----------------
__global__ __launch_bounds__(256) void cast_bf16_k(
    const float* __restrict__ g, const float* __restrict__ e,
    u16* __restrict__ og, u16* __restrict__ oe) {
  int i = blockIdx.x * 256 + threadIdx.x;
  float4 a = ((const float4*)g)[i];
  float4 b = ((const float4*)e)[i];
  ushort4 ua, ub;
  ua.x = f2bf(a.x); ua.y = f2bf(a.y); ua.z = f2bf(a.z); ua.w = f2bf(a.w);
  ub.x = f2bf(b.x); ub.y = f2bf(b.y); ub.z = f2bf(b.z); ub.w = f2bf(b.w);
  ((ushort4*)og)[i] = ua;
  ((ushort4*)oe)[i] = ub;
}

// ---------------- transpose + cast weights: W[K][512] -> WT[512][K] bf16 ----------------
__global__ __launch_bounds__(256) void wprep_k(
    const float* __restrict__ Wf, const float* __restrict__ Wq,
    const float* __restrict__ Wk, const float* __restrict__ Wv,
    const float* __restrict__ Wo,
    u16* __restrict__ WfT, u16* __restrict__ WqT, u16* __restrict__ WkT,
    u16* __restrict__ WvT, u16* __restrict__ WoT) {
  int z = blockIdx.z;
  const float* W; u16* WT; int K;
  switch (z) {
    case 0: W = Wf; WT = WfT; K = 1024; break;
    case 1: W = Wq; WT = WqT; K = 512; break;
    case 2: W = Wk; WT = WkT; K = 512; break;
    case 3: W = Wv; WT = WvT; K = 512; break;
    default: W = Wo; WT = WoT; K = 512; break;
  }
  int k0 = blockIdx.y * 32;
  if (k0 >= K) return;
  int n0 = blockIdx.x * 32;
  __shared__ float t[32][33];
  int tx = threadIdx.x & 31, ty = threadIdx.x >> 5;
#pragma unroll
  for (int i = 0; i < 32; i += 8)
    t[ty + i][tx] = W[(size_t)(k0 + ty + i) * DDIM + n0 + tx];
  __syncthreads();
#pragma unroll
  for (int i = 0; i < 32; i += 8)
    WT[(size_t)(n0 + ty + i) * K + k0 + tx] = f2bf(t[tx][ty + i]);
}

// ---------------- pack mask to 4-plane bits, float4 loads ----------------
__global__ __launch_bounds__(256) void mpack2_k(const float* __restrict__ M,
                                                u64* __restrict__ Mp) {
  int wid = (blockIdx.x * 256 + threadIdx.x) >> 6; // 2048 waves
  int lane = threadIdx.x & 63;
#pragma unroll 4
  for (int i = 0; i < 16; ++i) {
    int idx = wid * 16 + i; // 4096 rows x 8 col-groups
    int row = idx >> 3, k = idx & 7;
    float4 v = *(const float4*)&M[(size_t)row * SS + k * 256 + lane * 4];
    u64 b0 = __ballot(v.x != 0.0f);
    u64 b1 = __ballot(v.y != 0.0f);
    u64 b2 = __ballot(v.z != 0.0f);
    u64 b3 = __ballot(v.w != 0.0f);
    if (lane == 0) {
      u64* p = Mp + ((size_t)row * 32 + k * 4);
      p[0] = b0; p[1] = b1; p[2] = b2; p[3] = b3;
    }
  }
}

// ---------------- bf16 MFMA GEMM v2: BK=64, double-buffered 2-phase ---------
// C[M=4096][N=512] = A[M][K] @ Bt[N][K]^T + bias.  64x64 tile, 4 waves.
// Staging pattern identical to attn5's verified 64x64-tile swizzle.
// EPI 1 z==0 (Q): output pre-scaled by 0.125*log2(e) so attn uses exp2.
template <int EPI>
__global__ __launch_bounds__(256) void gemm2_k(
    const u16* __restrict__ A0, const u16* __restrict__ A1,
    const u16* __restrict__ Bt0, const u16* __restrict__ Bt1,
    const u16* __restrict__ Bt2,
    const float* __restrict__ bias0, const float* __restrict__ bias1,
    const float* __restrict__ bias2,
    u16* __restrict__ O0, u16* __restrict__ O1, u16* __restrict__ O2,
    float* __restrict__ OF) {
  constexpr int KSZ = (EPI == 0) ? 1024 : 512;
  constexpr int NIT = KSZ / 64;
  __shared__ alignas(16) u16 Al[2][64 * 64];
  __shared__ alignas(16) u16 Bl[2][64 * 64];

  const int tid = threadIdx.x;
  const int l = tid & 63, w = tid >> 6, lg = l >> 4, lr = l & 15;
  const int wm = w >> 1, wn = w & 1;
  const int m0 = blockIdx.y * 64;
  const int n0 = blockIdx.x * 64;

  const u16* Aa = A0; const u16* Bt = Bt0; const float* bias = bias0;
  int z = 0;
  if (EPI == 1) {
    z = blockIdx.z;
    Aa = (z == 2) ? A1 : A0;
    Bt = (z == 0) ? Bt0 : (z == 1) ? Bt1 : Bt2;
    bias = (z == 0) ? bias0 : (z == 1) ? bias1 : bias2;
  }

  f32x4 zero4 = {0.f, 0.f, 0.f, 0.f};
  f32x4 acc[2][2];
#pragma unroll
  for (int i = 0; i < 2; ++i)
#pragma unroll
    for (int j = 0; j < 2; ++j) acc[i][j] = zero4;

  // staging: 64 rows x 8 chunks of 16B; thread -> row tid/8 (+32), chunk tid&7
  const int srow = tid >> 3, spos = tid & 7;
  const int sk8 = spos ^ (srow & 7); // swizzled source chunk (involution)
  const size_t sdst = (size_t)tid * 16;

  // iteration-invariant fragment LDS offsets (read chunk c -> c^(row&7))
  int aOff[2][2], bOff[2][2];
#pragma unroll
  for (int i = 0; i < 2; ++i) {
    int row = 32 * wm + 16 * i + lr;
    aOff[i][0] = row * 128 + ((lg ^ (row & 7)) * 16);
    aOff[i][1] = row * 128 + (((4 + lg) ^ (row & 7)) * 16);
  }
#pragma unroll
  for (int j = 0; j < 2; ++j) {
    int row = 32 * wn + 16 * j + lr;
    bOff[j][0] = row * 128 + ((lg ^ (row & 7)) * 16);
    bOff[j][1] = row * 128 + (((4 + lg) ^ (row & 7)) * 16);
  }

  auto STAGE = [&](int buf, int kt) {
    int kbase = kt * 64 + 8 * sk8;
    const u16* sA;
    if (EPI == 0) {
      // K-tile of 64 never straddles the 512 concat boundary (kt<8 -> gene)
      const u16* Asrc = (kt < 8) ? A0 : A1;
      int kk = (kt < 8) ? kbase : kbase - 512;
      sA = Asrc + (size_t)(m0 + srow) * 512 + kk;
    } else {
      sA = Aa + (size_t)(m0 + srow) * 512 + kbase;
    }
    const u16* sB = Bt + (size_t)(n0 + srow) * KSZ + kbase;
    cp16(sA, (char*)Al[buf] + sdst);
    cp16(sA + 32 * 512, (char*)Al[buf] + sdst + 4096);
    cp16(sB, (char*)Bl[buf] + sdst);
    cp16(sB + 32 * KSZ, (char*)Bl[buf] + sdst + 4096);
  };

  // prologue
  STAGE(0, 0);
  asm volatile("s_waitcnt vmcnt(0)" ::: "memory");
  __syncthreads();

  int cur = 0;
  for (int kt = 0; kt < NIT; ++kt) {
    if (kt + 1 < NIT) STAGE(cur ^ 1, kt + 1); // overlaps compute below
    const char* Ab = (const char*)Al[cur];
    const char* Bb = (const char*)Bl[cur];
    bf16x8 af[2][2], bfr[2][2];
#pragma unroll
    for (int i = 0; i < 2; ++i) {
      af[i][0] = *(const bf16x8*)(Ab + aOff[i][0]);
      af[i][1] = *(const bf16x8*)(Ab + aOff[i][1]);
    }
#pragma unroll
    for (int j = 0; j < 2; ++j) {
      bfr[j][0] = *(const bf16x8*)(Bb + bOff[j][0]);
      bfr[j][1] = *(const bf16x8*)(Bb + bOff[j][1]);
    }
#pragma unroll
    for (int kk = 0; kk < 2; ++kk)
#pragma unroll
      for (int i = 0; i < 2; ++i)
#pragma unroll
        for (int j = 0; j < 2; ++j)
          acc[i][j] = __builtin_amdgcn_mfma_f32_16x16x32_bf16(
              af[i][kk], bfr[j][kk], acc[i][j], 0, 0, 0);
    asm volatile("s_waitcnt vmcnt(0)" ::: "memory");
    __syncthreads();
    cur ^= 1;
  }

  // epilogue: D row = 4*lg + r, col = lr (per 16x16 tile)
#pragma unroll
  for (int j = 0; j < 2; ++j) {
    int c = n0 + 32 * wn + 16 * j + lr;
    float bv = bias[c];
#pragma unroll
    for (int i = 0; i < 2; ++i) {
      int qb = m0 + 32 * wm + 16 * i + 4 * lg;
      if (EPI == 0) {
#pragma unroll
        for (int r = 0; r < 4; ++r)
          O0[(size_t)(qb + r) * 512 + c] = f2bf(acc[i][j][r] + bv);
      } else if (EPI == 2) {
#pragma unroll
        for (int r = 0; r < 4; ++r)
          OF[(size_t)(qb + r) * 512 + c] = acc[i][j][r] + bv;
      } else {
        int b = qb >> 11, s = qb & 2047;
        int hh = c >> 6, hd = c & 63;
        if (z < 2) {
          const float qsc = (z == 0) ? 0.18033688011112042f : 1.0f;
          u16* O = (z == 0) ? O0 : O1;
#pragma unroll
          for (int r = 0; r < 4; ++r)
            O[((size_t)(b * HH + hh) * SS + s + r) * HDD + hd] =
                f2bf((acc[i][j][r] + bv) * qsc);
        } else {
          ushort4 v;
          v.x = f2bf(acc[i][j][0] + bv);
          v.y = f2bf(acc[i][j][1] + bv);
          v.z = f2bf(acc[i][j][2] + bv);
          v.w = f2bf(acc[i][j][3] + bv);
          *(ushort4*)(O2 + ((size_t)(b * HH + hh) * HDD + hd) * SS + s) = v;
        }
      }
    }
  }
}

// ---------------- flash attention v5 (unchanged from r8, 65.9 us) ------------
__global__ __launch_bounds__(256) void attn5_k(
    const u16* __restrict__ Qh, const u16* __restrict__ Kh,
    const u16* __restrict__ Vt, const u64* __restrict__ Mp,
    u16* __restrict__ AO) {
  __shared__ alignas(16) u16 Kl[2][64 * 64];
  __shared__ alignas(16) u16 Vl[2][64 * 64];
  __shared__ alignas(16) u16 Pl[4][16 * 64];

  const int tid = threadIdx.x;
  const int l = tid & 63, w = tid >> 6, lg = l >> 4, lr = l & 15;
  const int bh = blockIdx.y, b = bh >> 3, h = bh & 7;
  const int qw = blockIdx.x * 64 + 16 * w;

  bf16x8 qf0, qf1;
  {
    const u16* qp = Qh + ((size_t)bh * SS + qw + lr) * HDD + 8 * lg;
    qf0 = *(const bf16x8*)qp;
    qf1 = *(const bf16x8*)(qp + 32);
  }

  f32x4 zero4 = {0.f, 0.f, 0.f, 0.f};
  f32x4 o[4];
#pragma unroll
  for (int t4 = 0; t4 < 4; ++t4) o[t4] = zero4;
  float mrun = -INFINITY, lrun = 0.f;

  const u64* Mrow = Mp + ((size_t)b * SS + qw + lr) * 32;
  u64 mp[4], mpN[4];
#pragma unroll
  for (int r = 0; r < 4; ++r) mp[r] = Mrow[r];

  int kOff[4][2], vOff[4][2], pOff[2], wOff[4];
#pragma unroll
  for (int g = 0; g < 4; ++g) {
    int krow = 16 * g + lr;
    kOff[g][0] = krow * 128 + ((lg ^ (krow & 7)) * 16);
    kOff[g][1] = krow * 128 + (((4 + lg) ^ (krow & 7)) * 16);
  }
#pragma unroll
  for (int t4 = 0; t4 < 4; ++t4) {
    int vrow = 16 * t4 + lr;
    vOff[t4][0] = vrow * 128 + ((lg ^ (vrow & 7)) * 16);
    vOff[t4][1] = vrow * 128 + (((4 + lg) ^ (vrow & 7)) * 16);
  }
#pragma unroll
  for (int kk = 0; kk < 2; ++kk)
    pOff[kk] = lr * 128 + (((4 * kk + lg) ^ (lr & 7)) * 16);
#pragma unroll
  for (int g = 0; g < 4; ++g)
    wOff[g] = lr * 128 + (((2 * g + (lg >> 1)) ^ (lr & 7)) * 16) + (lg & 1) * 8;

  const int srow = tid >> 3, spos = tid & 7;
  const int sk8 = spos ^ (srow & 7);
  const size_t sdst = (size_t)tid * 16;
  const u16* pK0 = Kh + ((size_t)bh * SS + srow) * HDD + 8 * sk8;
  const u16* pK1 = pK0 + 32 * HDD;
  const u16* pV0 = Vt + ((size_t)bh * HDD + srow) * SS + 8 * sk8;
  const u16* pV1 = pV0 + 32 * SS;

  cp16(pK0, (char*)Kl[0] + sdst);
  cp16(pK1, (char*)Kl[0] + sdst + 4096);
  cp16(pV0, (char*)Vl[0] + sdst);
  cp16(pV1, (char*)Vl[0] + sdst + 4096);
  asm volatile("s_waitcnt vmcnt(0)" ::: "memory");
  __syncthreads();

  u16* Pw = Pl[w];
  int cur = 0;
  for (int kt = 0; kt < 32; ++kt) {
    if (kt < 31) {
      pK0 += 64 * HDD; pK1 += 64 * HDD; pV0 += 64; pV1 += 64;
      char* kd = (char*)Kl[cur ^ 1];
      char* vd = (char*)Vl[cur ^ 1];
      cp16(pK0, kd + sdst);
      cp16(pK1, kd + sdst + 4096);
      cp16(pV0, vd + sdst);
      cp16(pV1, vd + sdst + 4096);
    }
    const int tm = kt & 3;
    if (tm == 0 && kt < 28) {
#pragma unroll
      for (int r = 0; r < 4; ++r) mpN[r] = Mrow[((kt >> 2) + 1) * 4 + r];
    }

    const char* Klw = (const char*)Kl[cur];
    const char* Vlw = (const char*)Vl[cur];

    f32x4 sc[4];
#pragma unroll
    for (int g = 0; g < 4; ++g) {
      bf16x8 k0f = *(const bf16x8*)(Klw + kOff[g][0]);
      bf16x8 k1f = *(const bf16x8*)(Klw + kOff[g][1]);
      f32x4 zz = zero4;
      zz = __builtin_amdgcn_mfma_f32_16x16x32_bf16(k0f, qf0, zz, 0, 0, 0);
      zz = __builtin_amdgcn_mfma_f32_16x16x32_bf16(k1f, qf1, zz, 0, 0, 0);
      sc[g] = zz;
    }
    {
      u32 wb[4];
#pragma unroll
      for (int r = 0; r < 4; ++r) wb[r] = (u32)(mp[r] >> (16 * tm + lg));
#pragma unroll
      for (int g = 0; g < 4; ++g)
#pragma unroll
        for (int r = 0; r < 4; ++r)
          if (!((wb[r] >> (4 * g)) & 1u)) sc[g][r] = -INFINITY;
    }
    float t = sc[0][0];
#pragma unroll
    for (int g = 0; g < 4; ++g)
#pragma unroll
      for (int r = 0; r < 4; ++r) t = fmaxf(t, sc[g][r]);
    t = fmaxf(t, __shfl_xor(t, 16));
    t = fmaxf(t, __shfl_xor(t, 32));
    float mnew = fmaxf(mrun, t);
    float fac = (mnew == -INFINITY) ? 1.0f : exp2f(mrun - mnew);
    float msafe = fmaxf(mnew, -1e30f);
    float psum = 0.f;
#pragma unroll
    for (int g = 0; g < 4; ++g)
#pragma unroll
      for (int r = 0; r < 4; ++r) {
        float p = exp2f(sc[g][r] - msafe);
        sc[g][r] = p;
        psum += p;
      }
    psum += __shfl_xor(psum, 16);
    psum += __shfl_xor(psum, 32);
    mrun = mnew;
    lrun = lrun * fac + psum;
#pragma unroll
    for (int t4 = 0; t4 < 4; ++t4) o[t4] *= fac;
#pragma unroll
    for (int g = 0; g < 4; ++g) {
      uint2 pv;
      pv.x = cvtpk(sc[g][0], sc[g][1]);
      pv.y = cvtpk(sc[g][2], sc[g][3]);
      *(uint2*)((char*)Pw + wOff[g]) = pv;
    }
#pragma unroll
    for (int kk = 0; kk < 2; ++kk) {
      bf16x8 pf = *(const bf16x8*)((const char*)Pw + pOff[kk]);
#pragma unroll
      for (int t4 = 0; t4 < 4; ++t4) {
        bf16x8 vf = *(const bf16x8*)(Vlw + vOff[t4][kk]);
        o[t4] = __builtin_amdgcn_mfma_f32_16x16x32_bf16(vf, pf, o[t4], 0, 0, 0);
      }
    }
    if (tm == 3) {
#pragma unroll
      for (int r = 0; r < 4; ++r) mp[r] = mpN[r];
    }
    asm volatile("s_waitcnt vmcnt(0)" ::: "memory");
    __syncthreads();
    cur ^= 1;
  }

  float inv = (lrun > 0.f) ? 1.0f / (lrun + 1e-8f) : 0.f;
  u16* op = AO + ((size_t)b * SS + qw + lr) * DDIM + h * HDD + 4 * lg;
#pragma unroll
  for (int t4 = 0; t4 < 4; ++t4) {
    ushort4 v;
    v.x = f2bf(o[t4][0] * inv);
    v.y = f2bf(o[t4][1] * inv);
    v.z = f2bf(o[t4][2] * inv);
    v.w = f2bf(o[t4][3] * inv);
    *(ushort4*)(op + 16 * t4) = v;
  }
}

// ---------------- launcher ----------------
extern "C" void kernel_launch(void* const* d_in, const int* in_sizes, int n_in,
                              void* d_out, int out_size, void* d_ws, size_t ws_size,
                              hipStream_t stream) {
  if (ws_size < (size_t)(31.5 * 1024 * 1024)) return;

  const float* gene = (const float*)d_in[0];
  const float* expr = (const float*)d_in[1];
  const float* Mm = (const float*)d_in[2];
  const float* Wf = (const float*)d_in[3];
  const float* bf = (const float*)d_in[4];
  const float* Wq = (const float*)d_in[5];
  const float* bq = (const float*)d_in[6];
  const float* Wk = (const float*)d_in[7];
  const float* bk = (const float*)d_in[8];
  const float* Wv = (const float*)d_in[9];
  const float* bv = (const float*)d_in[10];
  const float* Wo = (const float*)d_in[11];
  const float* bo = (const float*)d_in[12];
  float* out = (float*)d_out;

  char* ws = (char*)d_ws;
  const size_t MB4 = 4194304;
  u16* geneB = (u16*)(ws + 0 * MB4);
  u16* exprB = (u16*)(ws + 1 * MB4);
  u16* fusedB = (u16*)(ws + 2 * MB4);
  u16* QhB = (u16*)(ws + 3 * MB4);
  u16* KhB = (u16*)(ws + 4 * MB4);
  u16* VtB = (u16*)(ws + 5 * MB4);
  u16* attnB = (u16*)(ws + 6 * MB4);
  u16* WfT = (u16*)(ws + 7 * MB4);
  u16* WqT = (u16*)(ws + 7 * MB4 + 1048576);
  u16* WkT = (u16*)(ws + 7 * MB4 + 1048576 + 524288);
  u16* WvT = (u16*)(ws + 7 * MB4 + 1048576 + 2 * 524288);
  u16* WoT = (u16*)(ws + 7 * MB4 + 1048576 + 3 * 524288);
  u64* MpB = (u64*)(ws + 0 * MB4); // aliases geneB (dead after gemm2<0>)

  cast_bf16_k<<<2048, 256, 0, stream>>>(gene, expr, geneB, exprB);
  wprep_k<<<dim3(16, 32, 5), 256, 0, stream>>>(Wf, Wq, Wk, Wv, Wo, WfT, WqT,
                                               WkT, WvT, WoT);
  gemm2_k<0><<<dim3(8, 64), 256, 0, stream>>>(geneB, exprB, WfT, nullptr, nullptr,
                                              bf, nullptr, nullptr, fusedB,
                                              nullptr, nullptr, nullptr);
  mpack2_k<<<512, 256, 0, stream>>>(Mm, MpB);
  gemm2_k<1><<<dim3(8, 64, 3), 256, 0, stream>>>(fusedB, exprB, WqT, WkT, WvT,
                                                 bq, bk, bv, QhB, KhB, VtB,
                                                 nullptr);
  attn5_k<<<dim3(32, 16), 256, 0, stream>>>(QhB, KhB, VtB, MpB, attnB);
  gemm2_k<2><<<dim3(8, 64), 256, 0, stream>>>(attnB, nullptr, WoT, nullptr,
                                              nullptr, bo, nullptr, nullptr,
                                              nullptr, nullptr, nullptr, out);
}

// Round 11
// 205.937 us; speedup vs baseline: 1.0955x; 1.0955x over previous
//
#include <hip/hip_runtime.h>
#include <stdint.h>
#include <math.h>

#define BB 2
#define SS 2048
#define DDIM 512
#define HH 8
#define HDD 64

typedef unsigned short u16;
typedef unsigned int u32;
typedef unsigned long long u64;
typedef short bf16x8 __attribute__((ext_vector_type(8)));
typedef float f32x4 __attribute__((ext_vector_type(4)));

__device__ __forceinline__ u16 f2bf(float x) {
  unsigned int u = __float_as_uint(x);
  unsigned int r = (u + 0x7fffu + ((u >> 16) & 1u)) >> 16; // RNE
  return (u16)r;
}

__device__ __forceinline__ u32 cvtpk(float a, float b) {
  u32 r;
  asm("v_cvt_pk_bf16_f32 %0, %1, %2" : "=v"(r) : "v"(a), "v"(b));
  return r;
}

// async global->LDS, 16B per lane. LDS dest must be wave-uniform base + lane*16.
__device__ __forceinline__ void cp16(const void* g, void* l) {
  __builtin_amdgcn_global_load_lds(
      (const __attribute__((address_space(1))) void*)g,
      (__attribute__((address_space(3))) void*)l, 16, 0, 0);
}

// ---------------- prep: cast gene/expr (blocks 0..2047) + weight transpose
// (blocks 2048..4607, decomposed as bi = z*512 + y*16 + x) ----------------
__global__ __launch_bounds__(256) void prep_k(
    const float* __restrict__ gene, const float* __restrict__ expr,
    const float* __restrict__ Wf, const float* __restrict__ Wq,
    const float* __restrict__ Wk, const float* __restrict__ Wv,
    const float* __restrict__ Wo,
    u16* __restrict__ og, u16* __restrict__ oe,
    u16* __restrict__ WfT, u16* __restrict__ WqT, u16* __restrict__ WkT,
    u16* __restrict__ WvT, u16* __restrict__ WoT) {
  __shared__ float t[32][33];
  const int bid = blockIdx.x;
  if (bid < 2048) {
    int i = bid * 256 + threadIdx.x;
    float4 a = ((const float4*)gene)[i];
    float4 b = ((const float4*)expr)[i];
    ushort4 ua, ub;
    ua.x = f2bf(a.x); ua.y = f2bf(a.y); ua.z = f2bf(a.z); ua.w = f2bf(a.w);
    ub.x = f2bf(b.x); ub.y = f2bf(b.y); ub.z = f2bf(b.z); ub.w = f2bf(b.w);
    ((ushort4*)og)[i] = ua;
    ((ushort4*)oe)[i] = ub;
    return;
  }
  int bi = bid - 2048;
  int bx = bi & 15, by = (bi >> 4) & 31, bz = bi >> 9;
  const float* W; u16* WT; int K;
  switch (bz) {
    case 0: W = Wf; WT = WfT; K = 1024; break;
    case 1: W = Wq; WT = WqT; K = 512; break;
    case 2: W = Wk; WT = WkT; K = 512; break;
    case 3: W = Wv; WT = WvT; K = 512; break;
    default: W = Wo; WT = WoT; K = 512; break;
  }
  int k0 = by * 32;
  if (k0 >= K) return;
  int n0 = bx * 32;
  int tx = threadIdx.x & 31, ty = threadIdx.x >> 5;
#pragma unroll
  for (int i = 0; i < 32; i += 8)
    t[ty + i][tx] = W[(size_t)(k0 + ty + i) * DDIM + n0 + tx];
  __syncthreads();
#pragma unroll
  for (int i = 0; i < 32; i += 8)
    WT[(size_t)(n0 + ty + i) * K + k0 + tx] = f2bf(t[tx][ty + i]);
}

// ---------------- bf16 MFMA GEMM v2: BK=64, double-buffered (EPI 0 / 2) -----
template <int EPI>
__global__ __launch_bounds__(256) void gemm2_k(
    const u16* __restrict__ A0, const u16* __restrict__ A1,
    const u16* __restrict__ Bt0, const float* __restrict__ bias0,
    u16* __restrict__ O0, float* __restrict__ OF) {
  constexpr int KSZ = (EPI == 0) ? 1024 : 512;
  constexpr int NIT = KSZ / 64;
  __shared__ alignas(16) u16 Al[2][64 * 64];
  __shared__ alignas(16) u16 Bl[2][64 * 64];

  const int tid = threadIdx.x;
  const int l = tid & 63, w = tid >> 6, lg = l >> 4, lr = l & 15;
  const int wm = w >> 1, wn = w & 1;
  const int m0 = blockIdx.y * 64;
  const int n0 = blockIdx.x * 64;

  f32x4 zero4 = {0.f, 0.f, 0.f, 0.f};
  f32x4 acc[2][2];
#pragma unroll
  for (int i = 0; i < 2; ++i)
#pragma unroll
    for (int j = 0; j < 2; ++j) acc[i][j] = zero4;

  const int srow = tid >> 3, spos = tid & 7;
  const int sk8 = spos ^ (srow & 7);
  const size_t sdst = (size_t)tid * 16;

  int aOff[2][2], bOff[2][2];
#pragma unroll
  for (int i = 0; i < 2; ++i) {
    int row = 32 * wm + 16 * i + lr;
    aOff[i][0] = row * 128 + ((lg ^ (row & 7)) * 16);
    aOff[i][1] = row * 128 + (((4 + lg) ^ (row & 7)) * 16);
  }
#pragma unroll
  for (int j = 0; j < 2; ++j) {
    int row = 32 * wn + 16 * j + lr;
    bOff[j][0] = row * 128 + ((lg ^ (row & 7)) * 16);
    bOff[j][1] = row * 128 + (((4 + lg) ^ (row & 7)) * 16);
  }

  auto STAGE = [&](int buf, int kt) {
    int kbase = kt * 64 + 8 * sk8;
    const u16* sA;
    if (EPI == 0) {
      const u16* Asrc = (kt < 8) ? A0 : A1;
      int kk = (kt < 8) ? kbase : kbase - 512;
      sA = Asrc + (size_t)(m0 + srow) * 512 + kk;
    } else {
      sA = A0 + (size_t)(m0 + srow) * 512 + kbase;
    }
    const u16* sB = Bt0 + (size_t)(n0 + srow) * KSZ + kbase;
    cp16(sA, (char*)Al[buf] + sdst);
    cp16(sA + 32 * 512, (char*)Al[buf] + sdst + 4096);
    cp16(sB, (char*)Bl[buf] + sdst);
    cp16(sB + 32 * KSZ, (char*)Bl[buf] + sdst + 4096);
  };

  STAGE(0, 0);
  asm volatile("s_waitcnt vmcnt(0)" ::: "memory");
  __syncthreads();

  int cur = 0;
  for (int kt = 0; kt < NIT; ++kt) {
    if (kt + 1 < NIT) STAGE(cur ^ 1, kt + 1);
    const char* Ab = (const char*)Al[cur];
    const char* Bb = (const char*)Bl[cur];
    bf16x8 af[2][2], bfr[2][2];
#pragma unroll
    for (int i = 0; i < 2; ++i) {
      af[i][0] = *(const bf16x8*)(Ab + aOff[i][0]);
      af[i][1] = *(const bf16x8*)(Ab + aOff[i][1]);
    }
#pragma unroll
    for (int j = 0; j < 2; ++j) {
      bfr[j][0] = *(const bf16x8*)(Bb + bOff[j][0]);
      bfr[j][1] = *(const bf16x8*)(Bb + bOff[j][1]);
    }
#pragma unroll
    for (int kk = 0; kk < 2; ++kk)
#pragma unroll
      for (int i = 0; i < 2; ++i)
#pragma unroll
        for (int j = 0; j < 2; ++j)
          acc[i][j] = __builtin_amdgcn_mfma_f32_16x16x32_bf16(
              af[i][kk], bfr[j][kk], acc[i][j], 0, 0, 0);
    asm volatile("s_waitcnt vmcnt(0)" ::: "memory");
    __syncthreads();
    cur ^= 1;
  }

#pragma unroll
  for (int j = 0; j < 2; ++j) {
    int c = n0 + 32 * wn + 16 * j + lr;
    float bv = bias0[c];
#pragma unroll
    for (int i = 0; i < 2; ++i) {
      int qb = m0 + 32 * wm + 16 * i + 4 * lg;
      if (EPI == 0) {
#pragma unroll
        for (int r = 0; r < 4; ++r)
          O0[(size_t)(qb + r) * 512 + c] = f2bf(acc[i][j][r] + bv);
      } else {
#pragma unroll
        for (int r = 0; r < 4; ++r)
          OF[(size_t)(qb + r) * 512 + c] = acc[i][j][r] + bv;
      }
    }
  }
}

// ---------------- QKV GEMM (blocks 0..1535) + mask pack (1536..2047) --------
// z==0 (Q) pre-scaled by 0.125*log2(e).  Mp aliases geneB (dead here).
__global__ __launch_bounds__(256) void gemmqkv_k(
    const u16* __restrict__ A0 /*fused*/, const u16* __restrict__ A1 /*expr*/,
    const u16* __restrict__ Bt0, const u16* __restrict__ Bt1,
    const u16* __restrict__ Bt2,
    const float* __restrict__ bias0, const float* __restrict__ bias1,
    const float* __restrict__ bias2,
    u16* __restrict__ O0, u16* __restrict__ O1, u16* __restrict__ O2,
    const float* __restrict__ Mm, u64* __restrict__ Mp) {
  __shared__ alignas(16) u16 Al[2][64 * 64];
  __shared__ alignas(16) u16 Bl[2][64 * 64];

  const int bid = blockIdx.x;
  const int tid = threadIdx.x;
  if (bid >= 1536) {
    // ---- mask pack: Mp[row*32 + k*4 + p], bit i = (M[row][k*256+4i+p] != 0)
    int bi = bid - 1536;
    int wid = (bi * 256 + tid) >> 6;
    int lane = tid & 63;
#pragma unroll 4
    for (int i = 0; i < 16; ++i) {
      int idx = wid * 16 + i;
      int row = idx >> 3, k = idx & 7;
      float4 v = *(const float4*)&Mm[(size_t)row * SS + k * 256 + lane * 4];
      u64 b0 = __ballot(v.x != 0.0f);
      u64 b1 = __ballot(v.y != 0.0f);
      u64 b2 = __ballot(v.z != 0.0f);
      u64 b3 = __ballot(v.w != 0.0f);
      if (lane == 0) {
        u64* p = Mp + ((size_t)row * 32 + k * 4);
        p[0] = b0; p[1] = b1; p[2] = b2; p[3] = b3;
      }
    }
    return;
  }
  const int bx = bid & 7, by = (bid >> 3) & 63, bz = bid >> 9;
  const int l = tid & 63, w = tid >> 6, lg = l >> 4, lr = l & 15;
  const int wm = w >> 1, wn = w & 1;
  const int m0 = by * 64, n0 = bx * 64;

  const u16* Aa = (bz == 2) ? A1 : A0;
  const u16* Bt = (bz == 0) ? Bt0 : (bz == 1) ? Bt1 : Bt2;
  const float* bias = (bz == 0) ? bias0 : (bz == 1) ? bias1 : bias2;

  f32x4 zero4 = {0.f, 0.f, 0.f, 0.f};
  f32x4 acc[2][2];
#pragma unroll
  for (int i = 0; i < 2; ++i)
#pragma unroll
    for (int j = 0; j < 2; ++j) acc[i][j] = zero4;

  const int srow = tid >> 3, spos = tid & 7;
  const int sk8 = spos ^ (srow & 7);
  const size_t sdst = (size_t)tid * 16;

  int aOff[2][2], bOff[2][2];
#pragma unroll
  for (int i = 0; i < 2; ++i) {
    int row = 32 * wm + 16 * i + lr;
    aOff[i][0] = row * 128 + ((lg ^ (row & 7)) * 16);
    aOff[i][1] = row * 128 + (((4 + lg) ^ (row & 7)) * 16);
  }
#pragma unroll
  for (int j = 0; j < 2; ++j) {
    int row = 32 * wn + 16 * j + lr;
    bOff[j][0] = row * 128 + ((lg ^ (row & 7)) * 16);
    bOff[j][1] = row * 128 + (((4 + lg) ^ (row & 7)) * 16);
  }

  auto STAGE = [&](int buf, int kt) {
    int kbase = kt * 64 + 8 * sk8;
    const u16* sA = Aa + (size_t)(m0 + srow) * 512 + kbase;
    const u16* sB = Bt + (size_t)(n0 + srow) * 512 + kbase;
    cp16(sA, (char*)Al[buf] + sdst);
    cp16(sA + 32 * 512, (char*)Al[buf] + sdst + 4096);
    cp16(sB, (char*)Bl[buf] + sdst);
    cp16(sB + 32 * 512, (char*)Bl[buf] + sdst + 4096);
  };

  STAGE(0, 0);
  asm volatile("s_waitcnt vmcnt(0)" ::: "memory");
  __syncthreads();

  int cur = 0;
  for (int kt = 0; kt < 8; ++kt) {
    if (kt + 1 < 8) STAGE(cur ^ 1, kt + 1);
    const char* Ab = (const char*)Al[cur];
    const char* Bb = (const char*)Bl[cur];
    bf16x8 af[2][2], bfr[2][2];
#pragma unroll
    for (int i = 0; i < 2; ++i) {
      af[i][0] = *(const bf16x8*)(Ab + aOff[i][0]);
      af[i][1] = *(const bf16x8*)(Ab + aOff[i][1]);
    }
#pragma unroll
    for (int j = 0; j < 2; ++j) {
      bfr[j][0] = *(const bf16x8*)(Bb + bOff[j][0]);
      bfr[j][1] = *(const bf16x8*)(Bb + bOff[j][1]);
    }
#pragma unroll
    for (int kk = 0; kk < 2; ++kk)
#pragma unroll
      for (int i = 0; i < 2; ++i)
#pragma unroll
        for (int j = 0; j < 2; ++j)
          acc[i][j] = __builtin_amdgcn_mfma_f32_16x16x32_bf16(
              af[i][kk], bfr[j][kk], acc[i][j], 0, 0, 0);
    asm volatile("s_waitcnt vmcnt(0)" ::: "memory");
    __syncthreads();
    cur ^= 1;
  }

#pragma unroll
  for (int j = 0; j < 2; ++j) {
    int c = n0 + 32 * wn + 16 * j + lr;
    float bv = bias[c];
#pragma unroll
    for (int i = 0; i < 2; ++i) {
      int qb = m0 + 32 * wm + 16 * i + 4 * lg;
      int b = qb >> 11, s = qb & 2047;
      int hh = c >> 6, hd = c & 63;
      if (bz < 2) {
        const float qsc = (bz == 0) ? 0.18033688011112042f : 1.0f;
        u16* O = (bz == 0) ? O0 : O1;
#pragma unroll
        for (int r = 0; r < 4; ++r)
          O[((size_t)(b * HH + hh) * SS + s + r) * HDD + hd] =
              f2bf((acc[i][j][r] + bv) * qsc);
      } else {
        ushort4 v;
        v.x = f2bf(acc[i][j][0] + bv);
        v.y = f2bf(acc[i][j][1] + bv);
        v.z = f2bf(acc[i][j][2] + bv);
        v.w = f2bf(acc[i][j][3] + bv);
        *(ushort4*)(O2 + ((size_t)(b * HH + hh) * HDD + hd) * SS + s) = v;
      }
    }
  }
}

// ---------------- flash attention v6: 8 waves, 2-way KV split, lean core -----
// grid (32 qtiles, 16 bh), 512 threads. Waves 0-3: KV[0:1024), 4-7: [1024:2048)
// on the same 64 q-rows. Core identical to attn5 (r8-verified). Lane-local
// flash-merge at the end (fa/fb/inv all per-lane, zero shuffles).
__global__ __launch_bounds__(512) void attn6_k(
    const u16* __restrict__ Qh, const u16* __restrict__ Kh,
    const u16* __restrict__ Vt, const u64* __restrict__ Mp,
    u16* __restrict__ AO) {
  __shared__ alignas(16) u16 Kl[2][2][64 * 64]; // [kvhalf][buf]
  __shared__ alignas(16) u16 Vl[2][2][64 * 64];
  __shared__ alignas(16) u16 Pl[8][16 * 64];

  const int tid = threadIdx.x;
  const int l = tid & 63, w = tid >> 6, lg = l >> 4, lr = l & 15;
  const int qg = w & 3, kh = w >> 2;
  const int bh = blockIdx.y, b = bh >> 3, h = bh & 7;
  const int qw = blockIdx.x * 64 + 16 * qg;

  bf16x8 qf0, qf1;
  {
    const u16* qp = Qh + ((size_t)bh * SS + qw + lr) * HDD + 8 * lg;
    qf0 = *(const bf16x8*)qp;
    qf1 = *(const bf16x8*)(qp + 32);
  }

  f32x4 zero4 = {0.f, 0.f, 0.f, 0.f};
  f32x4 o[4];
#pragma unroll
  for (int t4 = 0; t4 < 4; ++t4) o[t4] = zero4;
  float mrun = -INFINITY, lrun = 0.f;

  const u64* Mrow = Mp + ((size_t)b * SS + qw + lr) * 32;
  u64 mp[4], mpN[4];
#pragma unroll
  for (int r = 0; r < 4; ++r) mp[r] = Mrow[16 * kh + r];

  int kOff[4][2], vOff[4][2], pOff[2], wOff[4];
#pragma unroll
  for (int g = 0; g < 4; ++g) {
    int krow = 16 * g + lr;
    kOff[g][0] = krow * 128 + ((lg ^ (krow & 7)) * 16);
    kOff[g][1] = krow * 128 + (((4 + lg) ^ (krow & 7)) * 16);
  }
#pragma unroll
  for (int t4 = 0; t4 < 4; ++t4) {
    int vrow = 16 * t4 + lr;
    vOff[t4][0] = vrow * 128 + ((lg ^ (vrow & 7)) * 16);
    vOff[t4][1] = vrow * 128 + (((4 + lg) ^ (vrow & 7)) * 16);
  }
#pragma unroll
  for (int kk = 0; kk < 2; ++kk)
    pOff[kk] = lr * 128 + (((4 * kk + lg) ^ (lr & 7)) * 16);
#pragma unroll
  for (int g = 0; g < 4; ++g)
    wOff[g] = lr * 128 + (((2 * g + (lg >> 1)) ^ (lr & 7)) * 16) + (lg & 1) * 8;

  // staging: 512 threads, 1 chunk per tile per thread (4 tiles: Ka,Kb,Va,Vb)
  const int srow = tid >> 3, spos = tid & 7;
  const int sk8 = spos ^ (srow & 7);
  const size_t sdst = (size_t)tid * 16;
  const u16* pKa = Kh + ((size_t)bh * SS + srow) * HDD + 8 * sk8;
  const u16* pKb = pKa + (size_t)1024 * HDD;
  const u16* pVa = Vt + ((size_t)bh * HDD + srow) * SS + 8 * sk8;
  const u16* pVb = pVa + 1024;

  cp16(pKa, (char*)Kl[0][0] + sdst);
  cp16(pKb, (char*)Kl[1][0] + sdst);
  cp16(pVa, (char*)Vl[0][0] + sdst);
  cp16(pVb, (char*)Vl[1][0] + sdst);
  asm volatile("s_waitcnt vmcnt(0)" ::: "memory");
  __syncthreads();

  u16* Pw = Pl[w];
  int cur = 0;
  for (int kt = 0; kt < 16; ++kt) {
    if (kt < 15) {
      pKa += 64 * HDD; pKb += 64 * HDD; pVa += 64; pVb += 64;
      cp16(pKa, (char*)Kl[0][cur ^ 1] + sdst);
      cp16(pKb, (char*)Kl[1][cur ^ 1] + sdst);
      cp16(pVa, (char*)Vl[0][cur ^ 1] + sdst);
      cp16(pVb, (char*)Vl[1][cur ^ 1] + sdst);
    }
    const int tm = kt & 3;
    if (tm == 0 && kt < 12) {
#pragma unroll
      for (int r = 0; r < 4; ++r)
        mpN[r] = Mrow[(4 * kh + (kt >> 2) + 1) * 4 + r];
    }

    const char* Klw = (const char*)Kl[kh][cur];
    const char* Vlw = (const char*)Vl[kh][cur];

    f32x4 sc[4];
#pragma unroll
    for (int g = 0; g < 4; ++g) {
      bf16x8 k0f = *(const bf16x8*)(Klw + kOff[g][0]);
      bf16x8 k1f = *(const bf16x8*)(Klw + kOff[g][1]);
      f32x4 zz = zero4;
      zz = __builtin_amdgcn_mfma_f32_16x16x32_bf16(k0f, qf0, zz, 0, 0, 0);
      zz = __builtin_amdgcn_mfma_f32_16x16x32_bf16(k1f, qf1, zz, 0, 0, 0);
      sc[g] = zz;
    }
    {
      u32 wb[4];
#pragma unroll
      for (int r = 0; r < 4; ++r) wb[r] = (u32)(mp[r] >> (16 * tm + lg));
#pragma unroll
      for (int g = 0; g < 4; ++g)
#pragma unroll
        for (int r = 0; r < 4; ++r)
          if (!((wb[r] >> (4 * g)) & 1u)) sc[g][r] = -INFINITY;
    }
    float t = sc[0][0];
#pragma unroll
    for (int g = 0; g < 4; ++g)
#pragma unroll
      for (int r = 0; r < 4; ++r) t = fmaxf(t, sc[g][r]);
    t = fmaxf(t, __shfl_xor(t, 16));
    t = fmaxf(t, __shfl_xor(t, 32));
    float mnew = fmaxf(mrun, t);
    float fac = (mnew == -INFINITY) ? 1.0f : exp2f(mrun - mnew);
    float msafe = fmaxf(mnew, -1e30f);
    float psum = 0.f;
#pragma unroll
    for (int g = 0; g < 4; ++g)
#pragma unroll
      for (int r = 0; r < 4; ++r) {
        float p = exp2f(sc[g][r] - msafe);
        sc[g][r] = p;
        psum += p;
      }
    psum += __shfl_xor(psum, 16);
    psum += __shfl_xor(psum, 32);
    mrun = mnew;
    lrun = lrun * fac + psum;
#pragma unroll
    for (int t4 = 0; t4 < 4; ++t4) o[t4] *= fac;
#pragma unroll
    for (int g = 0; g < 4; ++g) {
      uint2 pv;
      pv.x = cvtpk(sc[g][0], sc[g][1]);
      pv.y = cvtpk(sc[g][2], sc[g][3]);
      *(uint2*)((char*)Pw + wOff[g]) = pv;
    }
#pragma unroll
    for (int kk = 0; kk < 2; ++kk) {
      bf16x8 pf = *(const bf16x8*)((const char*)Pw + pOff[kk]);
#pragma unroll
      for (int t4 = 0; t4 < 4; ++t4) {
        bf16x8 vf = *(const bf16x8*)(Vlw + vOff[t4][kk]);
        o[t4] = __builtin_amdgcn_mfma_f32_16x16x32_bf16(vf, pf, o[t4], 0, 0, 0);
      }
    }
    if (tm == 3) {
#pragma unroll
      for (int r = 0; r < 4; ++r) mp[r] = mpN[r];
    }
    asm volatile("s_waitcnt vmcnt(0)" ::: "memory");
    __syncthreads();
    cur ^= 1;
  }

  // flash-merge halves: kh=1 posts partials (18 floats/thread), kh=0 combines.
  float* sh = (float*)&Kl[0][0][0]; // 18.4 KB scratch inside 64 KB K region
  if (kh == 1) {
    float* p = sh + (size_t)(qg * 64 + l) * 18;
    p[0] = mrun; p[1] = lrun;
#pragma unroll
    for (int t4 = 0; t4 < 4; ++t4)
#pragma unroll
      for (int r = 0; r < 4; ++r) p[2 + 4 * t4 + r] = o[t4][r];
  }
  __syncthreads();
  if (kh == 0) {
    const float* p = sh + (size_t)(qg * 64 + l) * 18;
    float mB = p[0], lB = p[1];
    float ms = fmaxf(mrun, mB);
    float fa = (mrun == -INFINITY) ? 0.f : exp2f(mrun - ms);
    float fb = (mB == -INFINITY) ? 0.f : exp2f(mB - ms);
    float ls = lrun * fa + lB * fb;
    float inv = (ls > 0.f) ? 1.0f / (ls + 1e-8f) : 0.f;
    u16* op = AO + ((size_t)b * SS + qw + lr) * DDIM + h * HDD + 4 * lg;
#pragma unroll
    for (int t4 = 0; t4 < 4; ++t4) {
      ushort4 v;
      v.x = f2bf((o[t4][0] * fa + p[2 + 4 * t4 + 0] * fb) * inv);
      v.y = f2bf((o[t4][1] * fa + p[2 + 4 * t4 + 1] * fb) * inv);
      v.z = f2bf((o[t4][2] * fa + p[2 + 4 * t4 + 2] * fb) * inv);
      v.w = f2bf((o[t4][3] * fa + p[2 + 4 * t4 + 3] * fb) * inv);
      *(ushort4*)(op + 16 * t4) = v;
    }
  }
}

// ---------------- launcher (5 kernels) ----------------
extern "C" void kernel_launch(void* const* d_in, const int* in_sizes, int n_in,
                              void* d_out, int out_size, void* d_ws, size_t ws_size,
                              hipStream_t stream) {
  if (ws_size < (size_t)(31.5 * 1024 * 1024)) return;

  const float* gene = (const float*)d_in[0];
  const float* expr = (const float*)d_in[1];
  const float* Mm = (const float*)d_in[2];
  const float* Wf = (const float*)d_in[3];
  const float* bf = (const float*)d_in[4];
  const float* Wq = (const float*)d_in[5];
  const float* bq = (const float*)d_in[6];
  const float* Wk = (const float*)d_in[7];
  const float* bk = (const float*)d_in[8];
  const float* Wv = (const float*)d_in[9];
  const float* bv = (const float*)d_in[10];
  const float* Wo = (const float*)d_in[11];
  const float* bo = (const float*)d_in[12];
  float* out = (float*)d_out;

  char* ws = (char*)d_ws;
  const size_t MB4 = 4194304;
  u16* geneB = (u16*)(ws + 0 * MB4);
  u16* exprB = (u16*)(ws + 1 * MB4);
  u16* fusedB = (u16*)(ws + 2 * MB4);
  u16* QhB = (u16*)(ws + 3 * MB4);
  u16* KhB = (u16*)(ws + 4 * MB4);
  u16* VtB = (u16*)(ws + 5 * MB4);
  u16* attnB = (u16*)(ws + 6 * MB4);
  u16* WfT = (u16*)(ws + 7 * MB4);
  u16* WqT = (u16*)(ws + 7 * MB4 + 1048576);
  u16* WkT = (u16*)(ws + 7 * MB4 + 1048576 + 524288);
  u16* WvT = (u16*)(ws + 7 * MB4 + 1048576 + 2 * 524288);
  u16* WoT = (u16*)(ws + 7 * MB4 + 1048576 + 3 * 524288);
  u64* MpB = (u64*)(ws + 0 * MB4); // aliases geneB (dead after gemm2<0>)

  prep_k<<<4608, 256, 0, stream>>>(gene, expr, Wf, Wq, Wk, Wv, Wo, geneB, exprB,
                                   WfT, WqT, WkT, WvT, WoT);
  gemm2_k<0><<<dim3(8, 64), 256, 0, stream>>>(geneB, exprB, WfT, bf, fusedB,
                                              nullptr);
  gemmqkv_k<<<2048, 256, 0, stream>>>(fusedB, exprB, WqT, WkT, WvT, bq, bk, bv,
                                      QhB, KhB, VtB, Mm, MpB);
  attn6_k<<<dim3(32, 16), 512, 0, stream>>>(QhB, KhB, VtB, MpB, attnB);
  gemm2_k<2><<<dim3(8, 64), 256, 0, stream>>>(attnB, nullptr, WoT, bo, nullptr,
                                              out);
}